// Round 1
// baseline (108.710 us; speedup 1.0000x reference)
//
#include <hip/hip_runtime.h>

// Problem constants (fixed by setup_inputs)
#define NB 16
#define NC 64
#define TX 128
#define TY 128
#define DD 768
#define BK 32
#define NT (DD / BK) // 24 K-steps

typedef __bf16 bf16x8 __attribute__((ext_vector_type(8)));
typedef float  f32x4  __attribute__((ext_vector_type(4)));

// fp32 -> bf16 round-to-nearest-even, pure integer (no libcall)
__device__ __forceinline__ unsigned short f2bf(float f) {
  unsigned u = __builtin_bit_cast(unsigned, f);
  return (unsigned short)((u + 0x7FFFu + ((u >> 16) & 1u)) >> 16);
}

// LDS tile: 128 rows x 32 bf16 = 64 B/row. XOR-swizzle the 16B slot index
// with (row>>1)&3 so the 16-lane fragment read (stride 64 B) lands at the
// free 2-way bank-conflict level instead of 8-way.
__device__ __forceinline__ unsigned swz(unsigned r, unsigned kb) {
  return r * 64u + ((((kb >> 4) & 3u) ^ ((r >> 1) & 3u)) << 4) + (kb & 15u);
}

__global__ __launch_bounds__(256, 2) void ur_score_kernel(
    const float* __restrict__ xs, const float* __restrict__ ys,
    float* __restrict__ out)
{
  // [buf][A=0/B=1][128 rows * 64 B]
  __shared__ char lds[2][2][8192];
  __shared__ float wsum[4];

  const int bc   = blockIdx.x;       // 0..1023 == b*64 + c
  const int b    = bc >> 6;
  const int tid  = threadIdx.x;
  const int lane = tid & 63;
  const int w    = tid >> 6;         // wave 0..3

  const float4* Ag = (const float4*)(xs + (size_t)b  * TX * DD);
  const float4* Bg = (const float4*)(ys + (size_t)bc * TY * DD);

  f32x4 acc[2][8];
  #pragma unroll
  for (int m = 0; m < 2; ++m)
    #pragma unroll
    for (int n = 0; n < 8; ++n)
      #pragma unroll
      for (int k = 0; k < 4; ++k)
        acc[m][n][k] = 0.0f;

  // Per-thread staging coords: 1024 float4 per tile / 256 threads = 4 each.
  unsigned rr[4], jj[4];
  #pragma unroll
  for (int i = 0; i < 4; ++i) {
    unsigned idx = (unsigned)tid + i * 256u;
    rr[i] = idx >> 3;   // row 0..127
    jj[i] = idx & 7u;   // float4 index within the 32-float K-slice
  }

  float4 pa[4], pb[4];

  // ---- prologue: stage K-step 0 into buf 0 ----
  #pragma unroll
  for (int i = 0; i < 4; ++i) {
    pa[i] = Ag[rr[i] * (DD / 4) + jj[i]];
    pb[i] = Bg[rr[i] * (DD / 4) + jj[i]];
  }
  #pragma unroll
  for (int i = 0; i < 4; ++i) {
    unsigned off = swz(rr[i], jj[i] * 8u);
    ushort4 qa, qb;
    qa.x = f2bf(pa[i].x); qa.y = f2bf(pa[i].y); qa.z = f2bf(pa[i].z); qa.w = f2bf(pa[i].w);
    qb.x = f2bf(pb[i].x); qb.y = f2bf(pb[i].y); qb.z = f2bf(pb[i].z); qb.w = f2bf(pb[i].w);
    *(ushort4*)&lds[0][0][off] = qa;
    *(ushort4*)&lds[0][1][off] = qb;
  }
  __syncthreads();

  const unsigned kb = ((unsigned)lane >> 4) << 4;          // 0/16/32/48 B
  const unsigned rA = (unsigned)(w * 32 + (lane & 15));    // A rows this wave
  const unsigned rB = (unsigned)(lane & 15);               // B rows (y)

  int cur = 0;
  for (int t = 0; t < NT; ++t) {
    // T14: issue next K-step's global loads before the MFMA phase
    if (t + 1 < NT) {
      const int kf = (t + 1) * (BK / 4);
      #pragma unroll
      for (int i = 0; i < 4; ++i) {
        pa[i] = Ag[rr[i] * (DD / 4) + kf + jj[i]];
        pb[i] = Bg[rr[i] * (DD / 4) + kf + jj[i]];
      }
    }

    // compute on buf[cur]
    bf16x8 af[2], bfr[8];
    af[0] = *(const bf16x8*)&lds[cur][0][swz(rA,      kb)];
    af[1] = *(const bf16x8*)&lds[cur][0][swz(rA + 16, kb)];
    #pragma unroll
    for (int n = 0; n < 8; ++n)
      bfr[n] = *(const bf16x8*)&lds[cur][1][swz(rB + n * 16u, kb)];
    #pragma unroll
    for (int m = 0; m < 2; ++m)
      #pragma unroll
      for (int n = 0; n < 8; ++n)
        acc[m][n] = __builtin_amdgcn_mfma_f32_16x16x32_bf16(af[m], bfr[n], acc[m][n], 0, 0, 0);

    // convert + write the prefetched tile into the other buffer
    if (t + 1 < NT) {
      #pragma unroll
      for (int i = 0; i < 4; ++i) {
        unsigned off = swz(rr[i], jj[i] * 8u);
        ushort4 qa, qb;
        qa.x = f2bf(pa[i].x); qa.y = f2bf(pa[i].y); qa.z = f2bf(pa[i].z); qa.w = f2bf(pa[i].w);
        qb.x = f2bf(pb[i].x); qb.y = f2bf(pb[i].y); qb.z = f2bf(pb[i].z); qb.w = f2bf(pb[i].w);
        *(ushort4*)&lds[cur ^ 1][0][off] = qa;
        *(ushort4*)&lds[cur ^ 1][1][off] = qb;
      }
    }
    __syncthreads();
    cur ^= 1;
  }

  // ---- reduction: max over y, sum over x ----
  // acc element (m,n,i) at lane l: x = w*32 + m*16 + (l>>4)*4 + i, y = n*16 + (l&15)
  float rm[2][4];
  #pragma unroll
  for (int m = 0; m < 2; ++m)
    #pragma unroll
    for (int i = 0; i < 4; ++i) {
      float v = acc[m][0][i];
      #pragma unroll
      for (int n = 1; n < 8; ++n) v = fmaxf(v, acc[m][n][i]);
      rm[m][i] = v;
    }
  // max across the 16 lanes holding different y for the same x-set
  #pragma unroll
  for (int mask = 1; mask < 16; mask <<= 1)
    #pragma unroll
    for (int m = 0; m < 2; ++m)
      #pragma unroll
      for (int i = 0; i < 4; ++i)
        rm[m][i] = fmaxf(rm[m][i], __shfl_xor(rm[m][i], mask, 64));

  // per-lane sum over its 8 distinct x rows, then combine the 4 lane-groups
  // (distinct x) without re-adding the 16-fold duplicates
  float ps = 0.0f;
  #pragma unroll
  for (int m = 0; m < 2; ++m)
    #pragma unroll
    for (int i = 0; i < 4; ++i) ps += rm[m][i];
  ps += __shfl_xor(ps, 16, 64);
  ps += __shfl_xor(ps, 32, 64);

  if (lane == 0) wsum[w] = ps;
  __syncthreads();
  if (tid == 0) out[bc] = wsum[0] + wsum[1] + wsum[2] + wsum[3];
}

extern "C" void kernel_launch(void* const* d_in, const int* in_sizes, int n_in,
                              void* d_out, int out_size, void* d_ws, size_t ws_size,
                              hipStream_t stream) {
  const float* xs = (const float*)d_in[0];
  const float* ys = (const float*)d_in[1];
  float* out = (float*)d_out;
  ur_score_kernel<<<dim3(NB * NC), dim3(256), 0, stream>>>(xs, ys, out);
}

// Round 2
// 93.984 us; speedup vs baseline: 1.1567x; 1.1567x over previous
//
#include <hip/hip_runtime.h>

// Problem constants (fixed by setup_inputs)
#define NB 16
#define NC 64
#define TX 128
#define TY 128
#define DD 768
#define BK 32
#define NT (DD / BK) // 24 K-steps

typedef __bf16 bf16_t;
typedef __bf16 bf16x8 __attribute__((ext_vector_type(8)));
typedef __bf16 bf16x4 __attribute__((ext_vector_type(4)));
typedef float  f32x4  __attribute__((ext_vector_type(4)));

// LDS tile: 128 rows x 32 bf16 = 64 B/row. XOR-swizzle the 16B slot index
// with (row>>1)&3 so the 16-lane fragment read (stride 64 B) lands at the
// free 2-way bank-conflict level instead of 8-way.
__device__ __forceinline__ unsigned swz(unsigned r, unsigned kb) {
  return r * 64u + ((((kb >> 4) & 3u) ^ ((r >> 1) & 3u)) << 4) + (kb & 15u);
}

// fp32x4 -> bf16x4 via compiler cast (emits v_cvt_pk_bf16_f32 pairs), 8B store
__device__ __forceinline__ void cvt_store(void* dst, float4 v) {
  bf16x4 q;
  q[0] = (bf16_t)v.x; q[1] = (bf16_t)v.y; q[2] = (bf16_t)v.z; q[3] = (bf16_t)v.w;
  *(bf16x4*)dst = q;
}

__global__ __launch_bounds__(256, 3) void ur_score_kernel(
    const float* __restrict__ xs, const float* __restrict__ ys,
    float* __restrict__ out)
{
  // [buf][A=0/B=1][128 rows * 64 B]
  __shared__ char lds[2][2][8192];
  __shared__ float wsum[4];

  // XCD-aware remap: u%16 == b, so u%8 == b%8 -> all 64 blocks sharing a
  // batch b land on one XCD; xs[b] (393 KB) stays L2-resident there.
  const int u  = blockIdx.x;
  const int b  = u & 15;
  const int c  = u >> 4;
  const int bc = b * NC + c;

  const int tid  = threadIdx.x;
  const int lane = tid & 63;
  const int w    = tid >> 6;         // wave 0..3

  const float4* Ag = (const float4*)(xs + (size_t)b  * TX * DD);
  const float4* Bg = (const float4*)(ys + (size_t)bc * TY * DD);

  f32x4 acc[2][8];
  #pragma unroll
  for (int m = 0; m < 2; ++m)
    #pragma unroll
    for (int n = 0; n < 8; ++n)
      #pragma unroll
      for (int k = 0; k < 4; ++k)
        acc[m][n][k] = 0.0f;

  // Per-thread staging coords: 1024 float4 per tile / 256 threads = 4 each.
  unsigned rr[4], jj[4];
  #pragma unroll
  for (int i = 0; i < 4; ++i) {
    unsigned idx = (unsigned)tid + i * 256u;
    rr[i] = idx >> 3;   // row 0..127
    jj[i] = idx & 7u;   // float4 index within the 32-float K-slice
  }

  float4 pa[4], pb[4];

  // ---- prologue: tile0 -> regs -> lds[0]; tile1 -> regs ----
  #pragma unroll
  for (int i = 0; i < 4; ++i) {
    pa[i] = Ag[rr[i] * (DD / 4) + jj[i]];
    pb[i] = Bg[rr[i] * (DD / 4) + jj[i]];
  }
  #pragma unroll
  for (int i = 0; i < 4; ++i) {
    unsigned off = swz(rr[i], jj[i] * 8u);
    cvt_store(&lds[0][0][off], pa[i]);
    cvt_store(&lds[0][1][off], pb[i]);
  }
  #pragma unroll
  for (int i = 0; i < 4; ++i) {
    pa[i] = Ag[rr[i] * (DD / 4) + (BK / 4) + jj[i]];
    pb[i] = Bg[rr[i] * (DD / 4) + (BK / 4) + jj[i]];
  }
  // barrier WITHOUT vmem drain: only LDS ops must be visible
  asm volatile("s_waitcnt lgkmcnt(0)" ::: "memory");
  __builtin_amdgcn_s_barrier();
  asm volatile("" ::: "memory");

  const unsigned kb = ((unsigned)lane >> 4) << 4;          // 0/16/32/48 B
  const unsigned rA = (unsigned)(w * 32 + (lane & 15));    // A rows this wave
  const unsigned rB = (unsigned)(lane & 15);               // B rows (y)

  int cur = 0;
  for (int t = 0; t < NT; ++t) {
    // 1) convert + write tile t+1 (its loads were issued a full iter ago)
    if (t + 1 < NT) {
      #pragma unroll
      for (int i = 0; i < 4; ++i) {
        unsigned off = swz(rr[i], jj[i] * 8u);
        cvt_store(&lds[cur ^ 1][0][off], pa[i]);
        cvt_store(&lds[cur ^ 1][1][off], pb[i]);
      }
    }
    // 2) issue tile t+2 loads; they stay in flight across the raw barrier
    if (t + 2 < NT) {
      const int kf = (t + 2) * (BK / 4);
      #pragma unroll
      for (int i = 0; i < 4; ++i) {
        pa[i] = Ag[rr[i] * (DD / 4) + kf + jj[i]];
        pb[i] = Bg[rr[i] * (DD / 4) + kf + jj[i]];
      }
    }
    // 3) fragments + MFMA on buf[cur]
    bf16x8 af0 = *(const bf16x8*)&lds[cur][0][swz(rA,      kb)];
    bf16x8 af1 = *(const bf16x8*)&lds[cur][0][swz(rA + 16, kb)];
    bf16x8 bfr[8];
    #pragma unroll
    for (int n = 0; n < 8; ++n)
      bfr[n] = *(const bf16x8*)&lds[cur][1][swz(rB + n * 16u, kb)];
    #pragma unroll
    for (int n = 0; n < 8; ++n)
      acc[0][n] = __builtin_amdgcn_mfma_f32_16x16x32_bf16(af0, bfr[n], acc[0][n], 0, 0, 0);
    #pragma unroll
    for (int n = 0; n < 8; ++n)
      acc[1][n] = __builtin_amdgcn_mfma_f32_16x16x32_bf16(af1, bfr[n], acc[1][n], 0, 0, 0);

    // barrier with LDS-only drain (prefetch vmem stays in flight)
    asm volatile("s_waitcnt lgkmcnt(0)" ::: "memory");
    __builtin_amdgcn_s_barrier();
    asm volatile("" ::: "memory");
    cur ^= 1;
  }

  // ---- reduction: max over y, sum over x ----
  // acc element (m,n,i) at lane l: x = w*32 + m*16 + (l>>4)*4 + i, y = n*16 + (l&15)
  float rm[2][4];
  #pragma unroll
  for (int m = 0; m < 2; ++m)
    #pragma unroll
    for (int i = 0; i < 4; ++i) {
      float v = acc[m][0][i];
      #pragma unroll
      for (int n = 1; n < 8; ++n) v = fmaxf(v, acc[m][n][i]);
      rm[m][i] = v;
    }
  // max across the 16 lanes holding different y for the same x-set
  #pragma unroll
  for (int mask = 1; mask < 16; mask <<= 1)
    #pragma unroll
    for (int m = 0; m < 2; ++m)
      #pragma unroll
      for (int i = 0; i < 4; ++i)
        rm[m][i] = fmaxf(rm[m][i], __shfl_xor(rm[m][i], mask, 64));

  // per-lane sum over its 8 distinct x rows, then combine the 4 lane-groups
  float ps = 0.0f;
  #pragma unroll
  for (int m = 0; m < 2; ++m)
    #pragma unroll
    for (int i = 0; i < 4; ++i) ps += rm[m][i];
  ps += __shfl_xor(ps, 16, 64);
  ps += __shfl_xor(ps, 32, 64);

  if (lane == 0) wsum[w] = ps;
  __syncthreads();
  if (tid == 0) out[bc] = wsum[0] + wsum[1] + wsum[2] + wsum[3];
}

extern "C" void kernel_launch(void* const* d_in, const int* in_sizes, int n_in,
                              void* d_out, int out_size, void* d_ws, size_t ws_size,
                              hipStream_t stream) {
  const float* xs = (const float*)d_in[0];
  const float* ys = (const float*)d_in[1];
  float* out = (float*)d_out;
  ur_score_kernel<<<dim3(NB * NC), dim3(256), 0, stream>>>(xs, ys, out);
}